// Round 1
// baseline (356.034 us; speedup 1.0000x reference)
//
#include <hip/hip_runtime.h>
#include <math.h>

constexpr int HD    = 32;     // head dim
constexpr int LW    = 256;    // tokens per window (M * N_CAND)
constexpr int NWIN  = 128;    // number of windows (= B_)
constexpr int ROWS  = NWIN * LW;   // 32768 total rows
constexpr int QKVC  = 384;    // qkv columns
constexpr float SCALE = 0.17677669529663687f;  // 1/sqrt(32)

__device__ inline float dot4(const float4 a, const float4 b) {
  return a.x * b.x + a.y * b.y + a.z * b.z + a.w * b.w;
}

// ---------------- RPE gather: rpe_g[h][i4*64+j4][0:96] ----------------
// s in [0,32): scale*q_rpe   [32,64): k_rpe   [64,96): v_rpe
__global__ __launch_bounds__(256) void rpe_gather_kernel(
    const float* __restrict__ tab, const int* __restrict__ rel_idx,
    float* __restrict__ out)
{
  int gid = blockIdx.x * 256 + threadIdx.x;   // 4*4096*96 = 1,572,864 exact
  int s   = gid % 96;
  int hp  = gid / 96;
  int p   = hp & 4095;
  int h   = hp >> 12;
  float v = tab[(size_t)rel_idx[p] * 384 + h * 96 + s];
  if (s < 32) v *= SCALE;
  out[gid] = v;
}

// ---------------- C[M,N] = A[M,K] @ W[N,K]^T + bias (LDS dbuf v3) -----------
// BM=BN=128, BK=8, 256 threads, 8x8 micro-tile.
// LDS tiles transposed [k][phys(m)], phys(m)=m+(m>>5)*4 (swizzle: the 16
// distinct tx*8 read addrs map 2 lanes/bank-cluster -> conflict-free; staging
// writes 2-way = free). Row stride 144. NO waves-per-EU cap (v2's 64-VGPR
// spill: acc[8][8] went to scratch -> 1.7 GB WRITE_SIZE).
template <int N, int K>
__global__ __launch_bounds__(256) void gemm_nt_bias_v3(
    const float* __restrict__ A, const float* __restrict__ W,
    const float* __restrict__ bias, float* __restrict__ C)
{
  constexpr int BK  = 8;
  constexpr int NS  = K / BK;
  constexpr int LDP = 144;
  __shared__ float As[2][BK][LDP];
  __shared__ float Ws[2][BK][LDP];

  const int tid  = threadIdx.x;
  const int tx   = tid & 15;          // n-dir, 8 cols each
  const int ty   = tid >> 4;          // m-dir, 8 rows each
  const int srow = tid >> 1;          // staging row 0..127
  const int skk  = (tid & 1) << 2;    // staging k base: 0 or 4
  const int sphys = srow + ((srow >> 5) << 2);

  const float* Ag = A + ((size_t)blockIdx.x * 128 + srow) * K + skk;
  const float* Wg = W + ((size_t)blockIdx.y * 128 + srow) * K + skk;

  float4 ra = *(const float4*)(Ag);
  float4 rw = *(const float4*)(Wg);
  As[0][skk + 0][sphys] = ra.x; As[0][skk + 1][sphys] = ra.y;
  As[0][skk + 2][sphys] = ra.z; As[0][skk + 3][sphys] = ra.w;
  Ws[0][skk + 0][sphys] = rw.x; Ws[0][skk + 1][sphys] = rw.y;
  Ws[0][skk + 2][sphys] = rw.z; Ws[0][skk + 3][sphys] = rw.w;
  __syncthreads();

  const int mA = ty * 8; const int pA = mA + ((mA >> 5) << 2);
  const int mB = tx * 8; const int pB = mB + ((mB >> 5) << 2);

  float acc[8][8] = {};

  for (int s = 0; s < NS; ++s) {
    const int cur = s & 1;
    if (s + 1 < NS) {
      const int k0 = (s + 1) * BK;
      ra = *(const float4*)(Ag + k0);
      rw = *(const float4*)(Wg + k0);
    }
#pragma unroll
    for (int k = 0; k < BK; ++k) {
      float4 a0 = *(const float4*)&As[cur][k][pA];
      float4 a1 = *(const float4*)&As[cur][k][pA + 4];
      float4 b0 = *(const float4*)&Ws[cur][k][pB];
      float4 b1 = *(const float4*)&Ws[cur][k][pB + 4];
      float av[8] = {a0.x, a0.y, a0.z, a0.w, a1.x, a1.y, a1.z, a1.w};
      float bv[8] = {b0.x, b0.y, b0.z, b0.w, b1.x, b1.y, b1.z, b1.w};
#pragma unroll
      for (int i = 0; i < 8; ++i)
#pragma unroll
        for (int j = 0; j < 8; ++j)
          acc[i][j] += av[i] * bv[j];
    }
    if (s + 1 < NS) {
      const int nxt = (s + 1) & 1;
      As[nxt][skk + 0][sphys] = ra.x; As[nxt][skk + 1][sphys] = ra.y;
      As[nxt][skk + 2][sphys] = ra.z; As[nxt][skk + 3][sphys] = ra.w;
      Ws[nxt][skk + 0][sphys] = rw.x; Ws[nxt][skk + 1][sphys] = rw.y;
      Ws[nxt][skk + 2][sphys] = rw.z; Ws[nxt][skk + 3][sphys] = rw.w;
      __syncthreads();
    }
  }

  const int crow = blockIdx.x * 128 + ty * 8;
  const int ccol = blockIdx.y * 128 + tx * 8;
  float4 bb0 = *(const float4*)(bias + ccol);
  float4 bb1 = *(const float4*)(bias + ccol + 4);
#pragma unroll
  for (int i = 0; i < 8; ++i) {
    float4 r0, r1;
    r0.x = acc[i][0] + bb0.x; r0.y = acc[i][1] + bb0.y;
    r0.z = acc[i][2] + bb0.z; r0.w = acc[i][3] + bb0.w;
    r1.x = acc[i][4] + bb1.x; r1.y = acc[i][5] + bb1.y;
    r1.z = acc[i][6] + bb1.z; r1.w = acc[i][7] + bb1.w;
    *(float4*)(C + (size_t)(crow + i) * N + ccol)     = r0;
    *(float4*)(C + (size_t)(crow + i) * N + ccol + 4) = r1;
  }
}

// ---------------- fused window attention (v2: 2-way KV-split) ----------------
// grid (NWIN, 4 heads), 512 threads. Group g = tid>>8 processes j4 in
// [g*32, g*32+32) over the SHARED 64KB K/V LDS tile, keeping its own online
// softmax partial (m, l, acc). Afterwards kvs is reused as a stride-37
// (conflict-free) combine buffer: group 1 deposits its partial, group 0
// merges and writes out. 8 waves/block x 2 blocks/CU -> 16 waves/CU (~50%
// occupancy vs 20% before) for latency hiding of the rp/ds/exp chains.
// Wave-uniform skip: a wave spans 16 aligned i4's; for shift-boundary
// row-band splits all lanes see the whole j4 block masked -> __all() skip.
__global__ __launch_bounds__(512, 4) void attn_kernel(
    const float* __restrict__ qkv, const float* __restrict__ rpeg,
    const float* __restrict__ mask, float* __restrict__ out)
{
  __shared__ float kvs[2 * LW * HD];   // K then V, 64 KB (reused for combine)
  const int b = blockIdx.x;
  const int h = blockIdx.y;
  const int tid = threadIdx.x;
  const int grp = tid >> 8;            // 0 or 1: which j4-half
  const int i   = tid & 255;           // query row
  const int i4  = i >> 2;
  const size_t rowbase = (size_t)b * LW;

  // stage K (cols 128+h*32) and V (cols 256+h*32) into LDS
  for (int it = 0; it < 4; ++it) {
    int f = tid + 512 * it;            // 0..2047
    int j = f >> 3, d4 = f & 7;
    const float* src = qkv + (rowbase + j) * QKVC + h * HD + d4 * 4;
    *(float4*)(&kvs[j * HD + d4 * 4])            = *(const float4*)(src + 128);
    *(float4*)(&kvs[LW * HD + j * HD + d4 * 4])  = *(const float4*)(src + 256);
  }
  __syncthreads();

  float4 q[8];
  {
    const float4* qr = (const float4*)(qkv + (rowbase + i) * QKVC + h * HD);
#pragma unroll
    for (int d = 0; d < 8; ++d) {
      float4 t = qr[d];
      q[d] = make_float4(t.x * SCALE, t.y * SCALE, t.z * SCALE, t.w * SCALE);
    }
  }
  const float4* rp4base =
      (const float4*)(rpeg + ((size_t)h * 4096 + (size_t)i4 * 64) * 96);
  const float* mrow = mask + ((size_t)b * LW + i) * LW;

  float4 acc[8];
#pragma unroll
  for (int d = 0; d < 8; ++d) acc[d] = make_float4(0.f, 0.f, 0.f, 0.f);
  float m_run = -INFINITY, l_run = 0.f;

  const int j4e = grp * 32 + 32;
  for (int j4 = grp * 32; j4 < j4e; ++j4) {
    float4 mv = *(const float4*)(mrow + j4 * 4);
    float mm = fmaxf(fmaxf(mv.x, mv.y), fmaxf(mv.z, mv.w));
    if (__all(mm < -1e8f)) continue;   // whole j4 block masked for this wave

    const float4* rp = rp4base + j4 * 24;   // 96 floats
    float4 u[8];
    float c0 = 0.f;
#pragma unroll
    for (int d = 0; d < 8; ++d) {
      float4 sq = rp[d];        // scale * q_rpe
      float4 kr = rp[8 + d];    // k_rpe
      u[d] = make_float4(q[d].x + sq.x, q[d].y + sq.y,
                         q[d].z + sq.z, q[d].w + sq.w);
      c0 += dot4(q[d], kr);
    }
    float mvals[4] = {mv.x, mv.y, mv.z, mv.w};
    float pool = 0.f;
#pragma unroll
    for (int jc = 0; jc < 4; ++jc) {
      const int j = j4 * 4 + jc;
      const float4* kj = (const float4*)(&kvs[j * HD]);
      float s = c0 + mvals[jc];
#pragma unroll
      for (int d = 0; d < 8; ++d) s += dot4(u[d], kj[d]);
      if (s > m_run) {
        float r = __expf(m_run - s);
        m_run = s;
        l_run *= r; pool *= r;
#pragma unroll
        for (int d = 0; d < 8; ++d) {
          acc[d].x *= r; acc[d].y *= r; acc[d].z *= r; acc[d].w *= r;
        }
      }
      float p = __expf(s - m_run);
      l_run += p; pool += p;
      const float4* vj = (const float4*)(&kvs[LW * HD + j * HD]);
#pragma unroll
      for (int d = 0; d < 8; ++d) {
        acc[d].x += p * vj[d].x; acc[d].y += p * vj[d].y;
        acc[d].z += p * vj[d].z; acc[d].w += p * vj[d].w;
      }
    }
#pragma unroll
    for (int d = 0; d < 8; ++d) {
      float4 vr = rp[16 + d];
      acc[d].x += pool * vr.x; acc[d].y += pool * vr.y;
      acc[d].z += pool * vr.z; acc[d].w += pool * vr.w;
    }
  }

  // ---- merge the two j-split partials via LDS (kvs reused) ----
  __syncthreads();                   // all waves done reading K/V
  constexpr int CST = 37;            // stride 37: coprime with 32 banks
  float* row = kvs + i * CST;
  if (grp == 1) {
    row[0] = m_run; row[1] = l_run;
#pragma unroll
    for (int d = 0; d < 8; ++d) {
      row[2 + 4 * d + 0] = acc[d].x; row[2 + 4 * d + 1] = acc[d].y;
      row[2 + 4 * d + 2] = acc[d].z; row[2 + 4 * d + 3] = acc[d].w;
    }
  }
  __syncthreads();
  if (grp == 0) {
    float m1 = row[0], l1 = row[1];
    float M  = fmaxf(m_run, m1);        // finite: diagonal j4 always present
    float r0 = __expf(m_run - M);       // expf(-inf)=0 handles empty partials
    float r1 = __expf(m1 - M);
    float inv = 1.f / (l_run * r0 + l1 * r1);
    float4* orow = (float4*)(out + (rowbase + i) * (4 * HD) + h * HD);
#pragma unroll
    for (int d = 0; d < 8; ++d) {
      float ax = row[2 + 4 * d + 0], ay = row[2 + 4 * d + 1];
      float az = row[2 + 4 * d + 2], aw = row[2 + 4 * d + 3];
      orow[d] = make_float4((acc[d].x * r0 + ax * r1) * inv,
                            (acc[d].y * r0 + ay * r1) * inv,
                            (acc[d].z * r0 + az * r1) * inv,
                            (acc[d].w * r0 + aw * r1) * inv);
    }
  }
}

extern "C" void kernel_launch(void* const* d_in, const int* in_sizes, int n_in,
                              void* d_out, int out_size, void* d_ws, size_t ws_size,
                              hipStream_t stream) {
  (void)in_sizes; (void)n_in; (void)out_size; (void)ws_size;
  const float* x         = (const float*)d_in[0];
  const float* qkv_w     = (const float*)d_in[1];
  const float* qkv_b     = (const float*)d_in[2];
  const float* rpe_table = (const float*)d_in[3];
  const float* proj_w    = (const float*)d_in[4];
  const float* proj_b    = (const float*)d_in[5];
  const float* attn_mask = (const float*)d_in[6];
  const int*   rel_idx   = (const int*)d_in[7];
  float* out = (float*)d_out;

  float* qkvbuf = (float*)d_ws;                          // 32768*384 fp32 (50.3 MB)
  float* rpeg   = qkvbuf + (size_t)ROWS * QKVC;          // 4*4096*96  (6.3 MB)
  float* attnb  = rpeg + (size_t)4 * 4096 * 96;          // 32768*128  (16.8 MB)

  hipLaunchKernelGGL(rpe_gather_kernel, dim3(6144), dim3(256), 0, stream,
                     rpe_table, rel_idx, rpeg);
  hipLaunchKernelGGL((gemm_nt_bias_v3<QKVC, 128>), dim3(ROWS / 128, QKVC / 128),
                     dim3(256), 0, stream, x, qkv_w, qkv_b, qkvbuf);
  hipLaunchKernelGGL(attn_kernel, dim3(NWIN, 4), dim3(512), 0, stream,
                     qkvbuf, rpeg, attn_mask, attnb);
  hipLaunchKernelGGL((gemm_nt_bias_v3<128, 128>), dim3(ROWS / 128, 1),
                     dim3(256), 0, stream, attnb, proj_w, proj_b, out);
}

// Round 2
// 346.573 us; speedup vs baseline: 1.0273x; 1.0273x over previous
//
#include <hip/hip_runtime.h>
#include <math.h>

constexpr int HD    = 32;     // head dim
constexpr int LW    = 256;    // tokens per window (M * N_CAND)
constexpr int NWIN  = 128;    // number of windows (= B_)
constexpr int ROWS  = NWIN * LW;   // 32768 total rows
constexpr int QKVC  = 384;    // qkv columns
constexpr float SCALE = 0.17677669529663687f;  // 1/sqrt(32)

__device__ inline float dot4(const float4 a, const float4 b) {
  return a.x * b.x + a.y * b.y + a.z * b.z + a.w * b.w;
}

// ---------------- RPE gather: rpe_g[h][i4*64+j4][0:96] ----------------
// s in [0,32): scale*q_rpe   [32,64): k_rpe   [64,96): v_rpe
__global__ __launch_bounds__(256) void rpe_gather_kernel(
    const float* __restrict__ tab, const int* __restrict__ rel_idx,
    float* __restrict__ out)
{
  int gid = blockIdx.x * 256 + threadIdx.x;   // 4*4096*96 = 1,572,864 exact
  int s   = gid % 96;
  int hp  = gid / 96;
  int p   = hp & 4095;
  int h   = hp >> 12;
  float v = tab[(size_t)rel_idx[p] * 384 + h * 96 + s];
  if (s < 32) v *= SCALE;
  out[gid] = v;
}

// ---------------- C[M,N] = A[M,K] @ W[N,K]^T + bias (LDS dbuf v3) -----------
// BM=BN=128, BK=8, 256 threads, 8x8 micro-tile.
// LDS tiles transposed [k][phys(m)], phys(m)=m+(m>>5)*4 (swizzle: the 16
// distinct tx*8 read addrs map 2 lanes/bank-cluster -> conflict-free; staging
// writes 2-way = free). Row stride 144. NO waves-per-EU cap (v2's 64-VGPR
// spill: acc[8][8] went to scratch -> 1.7 GB WRITE_SIZE).
template <int N, int K>
__global__ __launch_bounds__(256) void gemm_nt_bias_v3(
    const float* __restrict__ A, const float* __restrict__ W,
    const float* __restrict__ bias, float* __restrict__ C)
{
  constexpr int BK  = 8;
  constexpr int NS  = K / BK;
  constexpr int LDP = 144;
  __shared__ float As[2][BK][LDP];
  __shared__ float Ws[2][BK][LDP];

  const int tid  = threadIdx.x;
  const int tx   = tid & 15;          // n-dir, 8 cols each
  const int ty   = tid >> 4;          // m-dir, 8 rows each
  const int srow = tid >> 1;          // staging row 0..127
  const int skk  = (tid & 1) << 2;    // staging k base: 0 or 4
  const int sphys = srow + ((srow >> 5) << 2);

  const float* Ag = A + ((size_t)blockIdx.x * 128 + srow) * K + skk;
  const float* Wg = W + ((size_t)blockIdx.y * 128 + srow) * K + skk;

  float4 ra = *(const float4*)(Ag);
  float4 rw = *(const float4*)(Wg);
  As[0][skk + 0][sphys] = ra.x; As[0][skk + 1][sphys] = ra.y;
  As[0][skk + 2][sphys] = ra.z; As[0][skk + 3][sphys] = ra.w;
  Ws[0][skk + 0][sphys] = rw.x; Ws[0][skk + 1][sphys] = rw.y;
  Ws[0][skk + 2][sphys] = rw.z; Ws[0][skk + 3][sphys] = rw.w;
  __syncthreads();

  const int mA = ty * 8; const int pA = mA + ((mA >> 5) << 2);
  const int mB = tx * 8; const int pB = mB + ((mB >> 5) << 2);

  float acc[8][8] = {};

  for (int s = 0; s < NS; ++s) {
    const int cur = s & 1;
    if (s + 1 < NS) {
      const int k0 = (s + 1) * BK;
      ra = *(const float4*)(Ag + k0);
      rw = *(const float4*)(Wg + k0);
    }
#pragma unroll
    for (int k = 0; k < BK; ++k) {
      float4 a0 = *(const float4*)&As[cur][k][pA];
      float4 a1 = *(const float4*)&As[cur][k][pA + 4];
      float4 b0 = *(const float4*)&Ws[cur][k][pB];
      float4 b1 = *(const float4*)&Ws[cur][k][pB + 4];
      float av[8] = {a0.x, a0.y, a0.z, a0.w, a1.x, a1.y, a1.z, a1.w};
      float bv[8] = {b0.x, b0.y, b0.z, b0.w, b1.x, b1.y, b1.z, b1.w};
#pragma unroll
      for (int i = 0; i < 8; ++i)
#pragma unroll
        for (int j = 0; j < 8; ++j)
          acc[i][j] += av[i] * bv[j];
    }
    if (s + 1 < NS) {
      const int nxt = (s + 1) & 1;
      As[nxt][skk + 0][sphys] = ra.x; As[nxt][skk + 1][sphys] = ra.y;
      As[nxt][skk + 2][sphys] = ra.z; As[nxt][skk + 3][sphys] = ra.w;
      Ws[nxt][skk + 0][sphys] = rw.x; Ws[nxt][skk + 1][sphys] = rw.y;
      Ws[nxt][skk + 2][sphys] = rw.z; Ws[nxt][skk + 3][sphys] = rw.w;
      __syncthreads();
    }
  }

  const int crow = blockIdx.x * 128 + ty * 8;
  const int ccol = blockIdx.y * 128 + tx * 8;
  float4 bb0 = *(const float4*)(bias + ccol);
  float4 bb1 = *(const float4*)(bias + ccol + 4);
#pragma unroll
  for (int i = 0; i < 8; ++i) {
    float4 r0, r1;
    r0.x = acc[i][0] + bb0.x; r0.y = acc[i][1] + bb0.y;
    r0.z = acc[i][2] + bb0.z; r0.w = acc[i][3] + bb0.w;
    r1.x = acc[i][4] + bb1.x; r1.y = acc[i][5] + bb1.y;
    r1.z = acc[i][6] + bb1.z; r1.w = acc[i][7] + bb1.w;
    *(float4*)(C + (size_t)(crow + i) * N + ccol)     = r0;
    *(float4*)(C + (size_t)(crow + i) * N + ccol + 4) = r1;
  }
}

// ---------------- fused window attention (v3: 2-way KV-split, no spill) ------
// grid (NWIN, 4 heads), 512 threads. Group g = tid>>8 processes j4 in
// [g*32, g*32+32) over the SHARED 64KB K/V LDS tile, keeping its own online
// softmax partial (m, l, acc). Afterwards kvs is reused as a stride-37
// (conflict-free) combine buffer: group 1 deposits its partial, group 0
// merges and writes out.
// OCCUPANCY CONTRACT: LDS 64KB -> 2 blocks/CU = 16 waves/CU = 4 waves/SIMD.
// 4 waves/SIMD needs VGPR <= 128. __launch_bounds__(512, 2) caps at 256 so
// the compiler uses its natural ~90-110 (v1 was 88) -- the (512,4) variant
// capped VGPR at 64 and spilled acc/q to scratch (FETCH 66->145MB, dur +21%).
// Wave-uniform skip: a wave spans 16 aligned i4's; for shift-boundary
// windows whole j4 blocks are masked for all lanes -> __all() skip.
__global__ __launch_bounds__(512, 2) void attn_kernel(
    const float* __restrict__ qkv, const float* __restrict__ rpeg,
    const float* __restrict__ mask, float* __restrict__ out)
{
  __shared__ float kvs[2 * LW * HD];   // K then V, 64 KB (reused for combine)
  const int b = blockIdx.x;
  const int h = blockIdx.y;
  const int tid = threadIdx.x;
  const int grp = tid >> 8;            // 0 or 1: which j4-half
  const int i   = tid & 255;           // query row
  const int i4  = i >> 2;
  const size_t rowbase = (size_t)b * LW;

  // stage K (cols 128+h*32) and V (cols 256+h*32) into LDS
  for (int it = 0; it < 4; ++it) {
    int f = tid + 512 * it;            // 0..2047
    int j = f >> 3, d4 = f & 7;
    const float* src = qkv + (rowbase + j) * QKVC + h * HD + d4 * 4;
    *(float4*)(&kvs[j * HD + d4 * 4])            = *(const float4*)(src + 128);
    *(float4*)(&kvs[LW * HD + j * HD + d4 * 4])  = *(const float4*)(src + 256);
  }
  __syncthreads();

  float4 q[8];
  {
    const float4* qr = (const float4*)(qkv + (rowbase + i) * QKVC + h * HD);
#pragma unroll
    for (int d = 0; d < 8; ++d) {
      float4 t = qr[d];
      q[d] = make_float4(t.x * SCALE, t.y * SCALE, t.z * SCALE, t.w * SCALE);
    }
  }
  const float4* rp4base =
      (const float4*)(rpeg + ((size_t)h * 4096 + (size_t)i4 * 64) * 96);
  const float* mrow = mask + ((size_t)b * LW + i) * LW;

  float4 acc[8];
#pragma unroll
  for (int d = 0; d < 8; ++d) acc[d] = make_float4(0.f, 0.f, 0.f, 0.f);
  float m_run = -INFINITY, l_run = 0.f;

  const int j4e = grp * 32 + 32;
  for (int j4 = grp * 32; j4 < j4e; ++j4) {
    float4 mv = *(const float4*)(mrow + j4 * 4);
    float mm = fmaxf(fmaxf(mv.x, mv.y), fmaxf(mv.z, mv.w));
    if (__all(mm < -1e8f)) continue;   // whole j4 block masked for this wave

    const float4* rp = rp4base + j4 * 24;   // 96 floats
    float4 u[8];
    float c0 = 0.f;
#pragma unroll
    for (int d = 0; d < 8; ++d) {
      float4 sq = rp[d];        // scale * q_rpe
      float4 kr = rp[8 + d];    // k_rpe
      u[d] = make_float4(q[d].x + sq.x, q[d].y + sq.y,
                         q[d].z + sq.z, q[d].w + sq.w);
      c0 += dot4(q[d], kr);
    }
    float mvals[4] = {mv.x, mv.y, mv.z, mv.w};
    float pool = 0.f;
#pragma unroll
    for (int jc = 0; jc < 4; ++jc) {
      const int j = j4 * 4 + jc;
      const float4* kj = (const float4*)(&kvs[j * HD]);
      float s = c0 + mvals[jc];
#pragma unroll
      for (int d = 0; d < 8; ++d) s += dot4(u[d], kj[d]);
      if (s > m_run) {
        float r = __expf(m_run - s);
        m_run = s;
        l_run *= r; pool *= r;
#pragma unroll
        for (int d = 0; d < 8; ++d) {
          acc[d].x *= r; acc[d].y *= r; acc[d].z *= r; acc[d].w *= r;
        }
      }
      float p = __expf(s - m_run);
      l_run += p; pool += p;
      const float4* vj = (const float4*)(&kvs[LW * HD + j * HD]);
#pragma unroll
      for (int d = 0; d < 8; ++d) {
        acc[d].x += p * vj[d].x; acc[d].y += p * vj[d].y;
        acc[d].z += p * vj[d].z; acc[d].w += p * vj[d].w;
      }
    }
#pragma unroll
    for (int d = 0; d < 8; ++d) {
      float4 vr = rp[16 + d];
      acc[d].x += pool * vr.x; acc[d].y += pool * vr.y;
      acc[d].z += pool * vr.z; acc[d].w += pool * vr.w;
    }
  }

  // ---- merge the two j-split partials via LDS (kvs reused) ----
  __syncthreads();                   // all waves done reading K/V
  constexpr int CST = 37;            // stride 37: coprime with 32 banks
  float* row = kvs + i * CST;
  if (grp == 1) {
    row[0] = m_run; row[1] = l_run;
#pragma unroll
    for (int d = 0; d < 8; ++d) {
      row[2 + 4 * d + 0] = acc[d].x; row[2 + 4 * d + 1] = acc[d].y;
      row[2 + 4 * d + 2] = acc[d].z; row[2 + 4 * d + 3] = acc[d].w;
    }
  }
  __syncthreads();
  if (grp == 0) {
    float m1 = row[0], l1 = row[1];
    float M  = fmaxf(m_run, m1);        // finite: diagonal j4 always present
    float r0 = __expf(m_run - M);       // expf(-inf)=0 handles empty partials
    float r1 = __expf(m1 - M);
    float inv = 1.f / (l_run * r0 + l1 * r1);
    float4* orow = (float4*)(out + (rowbase + i) * (4 * HD) + h * HD);
#pragma unroll
    for (int d = 0; d < 8; ++d) {
      float ax = row[2 + 4 * d + 0], ay = row[2 + 4 * d + 1];
      float az = row[2 + 4 * d + 2], aw = row[2 + 4 * d + 3];
      orow[d] = make_float4((acc[d].x * r0 + ax * r1) * inv,
                            (acc[d].y * r0 + ay * r1) * inv,
                            (acc[d].z * r0 + az * r1) * inv,
                            (acc[d].w * r0 + aw * r1) * inv);
    }
  }
}

extern "C" void kernel_launch(void* const* d_in, const int* in_sizes, int n_in,
                              void* d_out, int out_size, void* d_ws, size_t ws_size,
                              hipStream_t stream) {
  (void)in_sizes; (void)n_in; (void)out_size; (void)ws_size;
  const float* x         = (const float*)d_in[0];
  const float* qkv_w     = (const float*)d_in[1];
  const float* qkv_b     = (const float*)d_in[2];
  const float* rpe_table = (const float*)d_in[3];
  const float* proj_w    = (const float*)d_in[4];
  const float* proj_b    = (const float*)d_in[5];
  const float* attn_mask = (const float*)d_in[6];
  const int*   rel_idx   = (const int*)d_in[7];
  float* out = (float*)d_out;

  float* qkvbuf = (float*)d_ws;                          // 32768*384 fp32 (50.3 MB)
  float* rpeg   = qkvbuf + (size_t)ROWS * QKVC;          // 4*4096*96  (6.3 MB)
  float* attnb  = rpeg + (size_t)4 * 4096 * 96;          // 32768*128  (16.8 MB)

  hipLaunchKernelGGL(rpe_gather_kernel, dim3(6144), dim3(256), 0, stream,
                     rpe_table, rel_idx, rpeg);
  hipLaunchKernelGGL((gemm_nt_bias_v3<QKVC, 128>), dim3(ROWS / 128, QKVC / 128),
                     dim3(256), 0, stream, x, qkv_w, qkv_b, qkvbuf);
  hipLaunchKernelGGL(attn_kernel, dim3(NWIN, 4), dim3(512), 0, stream,
                     qkvbuf, rpeg, attn_mask, attnb);
  hipLaunchKernelGGL((gemm_nt_bias_v3<128, 128>), dim3(ROWS / 128, 1),
                     dim3(256), 0, stream, attnb, proj_w, proj_b, out);
}